// Round 9
// baseline (2222.915 us; speedup 1.0000x reference)
//
#include <hip/hip_runtime.h>
#include <hip/hip_bf16.h>
#include <stdint.h>

#define B_DIM 4
#define NKK 4096
#define NQQ 4096
#define DD 64
#define HH 256

typedef __attribute__((ext_vector_type(4))) float floatx4;
typedef __attribute__((ext_vector_type(2))) float floatx2;
typedef __attribute__((ext_vector_type(8))) short bf16x8;

__device__ __forceinline__ float fexp2(float x) { return __builtin_amdgcn_exp2f(x); }
__device__ __forceinline__ unsigned fbits(float x) { return __float_as_uint(x); }
__device__ __forceinline__ float bf2f(unsigned short u) { return __uint_as_float(((unsigned)u) << 16); }
__device__ __forceinline__ unsigned short f2bf(float x) { return (unsigned short)(fbits(x) >> 16); }
__device__ __forceinline__ unsigned packbf(float a, float b) {
  return (fbits(a) >> 16) | (fbits(b) & 0xffff0000u);
}

// a - b on both packed halves in ONE VOP3P instruction (gfx950 has
// v_pk_add_f32 but no packed f32 max/abs -- abs lives on the consumer's
// input modifier).
__device__ __forceinline__ floatx2 pk_sub(floatx2 a, floatx2 b) {
  floatx2 d;
  asm("v_pk_add_f32 %0, %1, %2 neg_lo:[0,1] neg_hi:[0,1]" : "=v"(d) : "v"(a), "v"(b));
  return d;
}

// round-to-nearest-even split: x = h + l, h/l bf16, rel err ~2^-17
__device__ __forceinline__ void splitbf(float x, unsigned short& h, unsigned short& l) {
  unsigned u = fbits(x);
  unsigned hu = (u + 0x7fff + ((u >> 16) & 1)) & 0xffff0000u;
  h = (unsigned short)(hu >> 16);
  l = (unsigned short)(fbits(x - __uint_as_float(hu)) >> 16);
}

// f32 LDS tile row stride (floats): bank-start 4r mod 32; 8 consecutive rows
// span 8 distinct bank-quads -> conflict-free b128 (verified r4: 33.9M->2.85M).
#define FSTRIDE 68
#define FSTRIDE4 17
// P tile stride (shorts): 36 -> 72B rows; verified conflict-behavior in r8.
#define PSTRIDE 36

// ---------------------------------------------------------------------------
// Weight split prep.
// ---------------------------------------------------------------------------
__global__ __launch_bounds__(256) void wsplit_kernel(
    const float* __restrict__ W1a, const float* __restrict__ W2a, const float* __restrict__ W3a,
    const float* __restrict__ W1b, const float* __restrict__ W2b, const float* __restrict__ W3b,
    unsigned short* __restrict__ sp)
{
  int idx = blockIdx.x * 256 + threadIdx.x;       // 0..196607
  const int set = idx >= 98304;
  int r = idx - set * 98304;
  unsigned short* base = sp + (size_t)set * 196608;
  const float* src;
  unsigned short *dh, *dl;
  int j;
  if (r < 16384)      { src = set ? W1b : W1a; dh = base;          dl = base + 16384;  j = r; }
  else if (r < 81920) { src = set ? W2b : W2a; dh = base + 32768;  dl = base + 98304;  j = r - 16384; }
  else                { src = set ? W3b : W3a; dh = base + 163840; dl = base + 180224; j = r - 81920; }
  unsigned short h, l;
  splitbf(src[j], h, l);
  dh[j] = h; dl[j] = l;
}

// ---------------------------------------------------------------------------
// V pre-transpose: Vt[b][d][k] = bf16(V[b][k][d]).
// ---------------------------------------------------------------------------
__global__ __launch_bounds__(256) void vtrans_kernel(
    const float* __restrict__ V, unsigned short* __restrict__ Vt)
{
  __shared__ unsigned short t[64][80];
  const int tid = threadIdx.x;
  const int b = blockIdx.y;
  const int k0 = blockIdx.x * 64;
  const float4* V4 = (const float4*)V;
  {
    const int r = tid & 63;
    const int c4 = tid >> 6;
#pragma unroll
    for (int j = 0; j < 4; ++j) {
      float4 f = V4[((size_t)(b * NKK + k0 + r)) * 16 + c4 * 4 + j];
      const int d0 = c4 * 16 + j * 4;
      t[d0 + 0][r] = f2bf(f.x);
      t[d0 + 1][r] = f2bf(f.y);
      t[d0 + 2][r] = f2bf(f.z);
      t[d0 + 3][r] = f2bf(f.w);
    }
  }
  __syncthreads();
  {
    const int d = tid >> 2;
    const int kc = tid & 3;
    uint4 u0 = *(const uint4*)&t[d][kc * 16];
    uint4 u1 = *(const uint4*)&t[d][kc * 16 + 8];
    unsigned short* dst = Vt + ((size_t)(b * 64 + d)) * NKK + k0 + kc * 16;
    *(uint4*)dst = u0;
    *(uint4*)(dst + 8) = u1;
  }
}

// ---------------------------------------------------------------------------
// MLP on MFMA, split-bf16 (hh+lh+hl). 64 tokens/WG, 512 threads (8 waves).
// Round-9: X LDS tiles dropped (L1 A-frags split from global in registers,
// mulx re-reads X from L2) -> LDS 84 -> 66 KB -> 2 blocks/CU.
// ---------------------------------------------------------------------------
#define HSTRIDE 264   // shorts; 528B = 132 dwords = 4 mod 32 -> 2-way (free)
__global__ __launch_bounds__(512, 2) void mlpmm_kernel(
    const float* __restrict__ KEY, const float* __restrict__ QUERY,
    const float* __restrict__ B1a, const float* __restrict__ B2a, const float* __restrict__ B3a,
    const float* __restrict__ B1b, const float* __restrict__ B2b, const float* __restrict__ B3b,
    const unsigned short* __restrict__ sp,
    float* __restrict__ Ks, float* __restrict__ Qs, float* __restrict__ Wo)
{
  __shared__ unsigned short Hsh[64][HSTRIDE], Hsl[64][HSTRIDE]; // 66 KB
  const int tid = threadIdx.x;
  const int w = tid >> 6;        // 0..7
  const int lane = tid & 63;
  const int l15 = lane & 15;
  const int quad = lane >> 4;

  const int g = blockIdx.x;
  const float* X;
  float* outp;
  int mulx, t0;
  const unsigned short* wb;
  const float *b1, *b2, *b3;
  if (g < 256)      { X = KEY;   outp = Ks; mulx = 1; t0 = g * 64;         wb = sp;          b1 = B1a; b2 = B2a; b3 = B3a; }
  else if (g < 512) { X = QUERY; outp = Qs; mulx = 1; t0 = (g - 256) * 64; wb = sp;          b1 = B1a; b2 = B2a; b3 = B3a; }
  else              { X = QUERY; outp = Wo; mulx = 0; t0 = (g - 512) * 64; wb = sp + 196608; b1 = B1b; b2 = B2b; b3 = B3b; }
  const unsigned short* W1h = wb;
  const unsigned short* W1l = wb + 16384;
  const unsigned short* W2h = wb + 32768;
  const unsigned short* W2l = wb + 98304;
  const unsigned short* W3h = wb + 163840;
  const unsigned short* W3l = wb + 180224;
  const float4* X4 = (const float4*)X;

  // ---- layer 1: [64x64] x [64->256]; A-frags from global, split on the fly ----
  {
    floatx4 acc[4][2];
#pragma unroll
    for (int nb = 0; nb < 2; ++nb) {
      const float bias = b1[(w * 2 + nb) * 16 + l15];
#pragma unroll
      for (int mb = 0; mb < 4; ++mb) acc[mb][nb] = (floatx4){bias, bias, bias, bias};
    }
#pragma unroll
    for (int kb = 0; kb < 2; ++kb) {
      bf16x8 Ah[4], Al[4];
#pragma unroll
      for (int mb = 0; mb < 4; ++mb) {
        float4 x0 = X4[(size_t)(t0 + mb * 16 + l15) * 16 + kb * 8 + quad * 2];
        float4 x1 = X4[(size_t)(t0 + mb * 16 + l15) * 16 + kb * 8 + quad * 2 + 1];
        float v[8] = {x0.x, x0.y, x0.z, x0.w, x1.x, x1.y, x1.z, x1.w};
        unsigned short hs[8], ls[8];
#pragma unroll
        for (int e = 0; e < 8; ++e) splitbf(v[e], hs[e], ls[e]);
        uint4 uh = make_uint4(hs[0] | ((unsigned)hs[1] << 16), hs[2] | ((unsigned)hs[3] << 16),
                              hs[4] | ((unsigned)hs[5] << 16), hs[6] | ((unsigned)hs[7] << 16));
        uint4 ul = make_uint4(ls[0] | ((unsigned)ls[1] << 16), ls[2] | ((unsigned)ls[3] << 16),
                              ls[4] | ((unsigned)ls[5] << 16), ls[6] | ((unsigned)ls[7] << 16));
        Ah[mb] = __builtin_bit_cast(bf16x8, uh);
        Al[mb] = __builtin_bit_cast(bf16x8, ul);
      }
#pragma unroll
      for (int nb = 0; nb < 2; ++nb) {
        const int n0 = (w * 2 + nb) * 16;
        bf16x8 Bh = *(const bf16x8*)&W1h[(size_t)(n0 + l15) * 64 + kb * 32 + quad * 8];
        bf16x8 Bl = *(const bf16x8*)&W1l[(size_t)(n0 + l15) * 64 + kb * 32 + quad * 8];
#pragma unroll
        for (int mb = 0; mb < 4; ++mb) {
          acc[mb][nb] = __builtin_amdgcn_mfma_f32_16x16x32_bf16(Ah[mb], Bh, acc[mb][nb], 0, 0, 0);
          acc[mb][nb] = __builtin_amdgcn_mfma_f32_16x16x32_bf16(Al[mb], Bh, acc[mb][nb], 0, 0, 0);
          acc[mb][nb] = __builtin_amdgcn_mfma_f32_16x16x32_bf16(Ah[mb], Bl, acc[mb][nb], 0, 0, 0);
        }
      }
    }
#pragma unroll
    for (int mb = 0; mb < 4; ++mb)
#pragma unroll
      for (int nb = 0; nb < 2; ++nb) {
        const int col = (w * 2 + nb) * 16 + l15;
#pragma unroll
        for (int r = 0; r < 4; ++r) {
          const int row = mb * 16 + quad * 4 + r;
          float v = fmaxf(acc[mb][nb][r], 0.0f);
          unsigned short h, l;
          splitbf(v, h, l);
          Hsh[row][col] = h;
          Hsl[row][col] = l;
        }
      }
  }
  __syncthreads();

  // ---- layer 2: [64x256] x [256->256] ----
  {
    floatx4 acc2[4][2];
#pragma unroll
    for (int nb = 0; nb < 2; ++nb) {
      const float bias = b2[(w * 2 + nb) * 16 + l15];
#pragma unroll
      for (int mb = 0; mb < 4; ++mb) acc2[mb][nb] = (floatx4){bias, bias, bias, bias};
    }
#pragma unroll
    for (int kb = 0; kb < 8; ++kb) {
      bf16x8 Ah[4], Al[4];
#pragma unroll
      for (int mb = 0; mb < 4; ++mb) {
        Ah[mb] = *(const bf16x8*)&Hsh[mb * 16 + l15][kb * 32 + quad * 8];
        Al[mb] = *(const bf16x8*)&Hsl[mb * 16 + l15][kb * 32 + quad * 8];
      }
#pragma unroll
      for (int nb = 0; nb < 2; ++nb) {
        const int n0 = (w * 2 + nb) * 16;
        bf16x8 Bh = *(const bf16x8*)&W2h[(size_t)(n0 + l15) * 256 + kb * 32 + quad * 8];
        bf16x8 Bl = *(const bf16x8*)&W2l[(size_t)(n0 + l15) * 256 + kb * 32 + quad * 8];
#pragma unroll
        for (int mb = 0; mb < 4; ++mb) {
          acc2[mb][nb] = __builtin_amdgcn_mfma_f32_16x16x32_bf16(Ah[mb], Bh, acc2[mb][nb], 0, 0, 0);
          acc2[mb][nb] = __builtin_amdgcn_mfma_f32_16x16x32_bf16(Al[mb], Bh, acc2[mb][nb], 0, 0, 0);
          acc2[mb][nb] = __builtin_amdgcn_mfma_f32_16x16x32_bf16(Ah[mb], Bl, acc2[mb][nb], 0, 0, 0);
        }
      }
    }
    __syncthreads();
#pragma unroll
    for (int mb = 0; mb < 4; ++mb)
#pragma unroll
      for (int nb = 0; nb < 2; ++nb) {
        const int col = (w * 2 + nb) * 16 + l15;
#pragma unroll
        for (int r = 0; r < 4; ++r) {
          const int row = mb * 16 + quad * 4 + r;
          float v = fmaxf(acc2[mb][nb][r], 0.0f);
          unsigned short h, l;
          splitbf(v, h, l);
          Hsh[row][col] = h;
          Hsl[row][col] = l;
        }
      }
  }
  __syncthreads();

  // ---- layer 3: [64x256] x [256->64] ----
  {
    const int mp = (w >> 2) * 2;
    const int n0 = (w & 3) * 16;
    const float bias = b3[n0 + l15];
    floatx4 acc3[2];
#pragma unroll
    for (int m = 0; m < 2; ++m) acc3[m] = (floatx4){bias, bias, bias, bias};
#pragma unroll
    for (int kb = 0; kb < 8; ++kb) {
      bf16x8 Ah[2], Al[2];
#pragma unroll
      for (int m = 0; m < 2; ++m) {
        Ah[m] = *(const bf16x8*)&Hsh[(mp + m) * 16 + l15][kb * 32 + quad * 8];
        Al[m] = *(const bf16x8*)&Hsl[(mp + m) * 16 + l15][kb * 32 + quad * 8];
      }
      bf16x8 Bh = *(const bf16x8*)&W3h[(size_t)(n0 + l15) * 256 + kb * 32 + quad * 8];
      bf16x8 Bl = *(const bf16x8*)&W3l[(size_t)(n0 + l15) * 256 + kb * 32 + quad * 8];
#pragma unroll
      for (int m = 0; m < 2; ++m) {
        acc3[m] = __builtin_amdgcn_mfma_f32_16x16x32_bf16(Ah[m], Bh, acc3[m], 0, 0, 0);
        acc3[m] = __builtin_amdgcn_mfma_f32_16x16x32_bf16(Al[m], Bh, acc3[m], 0, 0, 0);
        acc3[m] = __builtin_amdgcn_mfma_f32_16x16x32_bf16(Ah[m], Bl, acc3[m], 0, 0, 0);
      }
    }
#pragma unroll
    for (int m = 0; m < 2; ++m)
#pragma unroll
      for (int r = 0; r < 4; ++r) {
        const int row = (mp + m) * 16 + quad * 4 + r;
        const int col = n0 + l15;
        float v = acc3[m][r];
        if (mulx) v *= X[(size_t)(t0 + row) * 64 + col];
        outp[(size_t)(t0 + row) * 64 + col] = v;
      }
  }
}

// ---------------------------------------------------------------------------
// Flash attention over L1-distance scores.
// Round-9: 16-key subtiles (ksA halves -> LDS 35 KB -> 4 blocks/CU), keys
// processed in PAIRS of subtiles with ONE 16x16x32 MFMA per 32 keys; m-updates
// between subtiles handled by rare RMW-rescale of stored P; wave-uniform
// __any skip-branch removes alpha work once m stabilizes (max is monotone).
// z=4 key split (grid 2048 = 2 exact rounds at 4 blocks/CU); partial O in
// bf16 to keep ws <= 24.4 MB. Direct single-pass fallback (z=1, PAIRS=32).
// ---------------------------------------------------------------------------
template <int PAIRS, bool PARTIAL>
__global__ __launch_bounds__(256, 4) void attn_kernel(
    const float* __restrict__ Ksg, const float* __restrict__ Qsg,
    const unsigned short* __restrict__ Vtg, const float* __restrict__ Wog,
    float* __restrict__ outp,
    float* __restrict__ Pm, float* __restrict__ Pl, unsigned short* __restrict__ POu)
{
  __shared__ float qsA[32 * FSTRIDE];              // 8704 B; epilogue: O merge buf
  __shared__ float ksA[4][16 * FSTRIDE];           // 17408 B
  __shared__ unsigned short psB[4][32 * PSTRIDE];  // 9216 B; epilogue: m/l overlay
  __shared__ float abA[4][32];                     // 512 B
  // total 35840 B -> 4 blocks/CU (4 x 36KB rounded = 144 KB <= 160 KB)

  const int tid  = threadIdx.x;
  const int w    = tid >> 6;
  const int lane = tid & 63;
  const int lq   = lane >> 3;
  const int lk   = lane & 7;
  const int l15  = lane & 15;
  const int quad = lane >> 4;
  const int b    = blockIdx.y;
  const int qt   = blockIdx.x * 32;

  {
    const int row = tid >> 3;
    const int c0  = (tid & 7) * 2;
    const float4* Q4 = (const float4*)Qsg;
    float4 g0 = Q4[(size_t)(b * NQQ + qt + row) * 16 + c0];
    float4 g1 = Q4[(size_t)(b * NQQ + qt + row) * 16 + c0 + 1];
    *(float4*)&qsA[row * FSTRIDE + c0 * 4]     = g0;
    *(float4*)&qsA[row * FSTRIDE + c0 * 4 + 4] = g1;
  }
  __syncthreads();

  float m_i[4], l_i[4], m_mfma[4];
  floatx4 acc[2][4];
#pragma unroll
  for (int i = 0; i < 4; ++i) { m_i[i] = -3.0e38f; l_i[i] = 0.0f; m_mfma[i] = -3.0e38f; }
#pragma unroll
  for (int mb = 0; mb < 2; ++mb)
#pragma unroll
    for (int nb = 0; nb < 4; ++nb)
#pragma unroll
      for (int r = 0; r < 4; ++r) acc[mb][nb][r] = 0.0f;

  const int kstart = PARTIAL ? (blockIdx.z * 4 + w) * (PAIRS * 32) : w * (PAIRS * 32);
  const float4* K4 = (const float4*)Ksg;
  const float NEG_HALF_LOG2E = -0.72134752044448170f;  // -0.5*log2(e)

  const int krow = (lane >> 4);   // 0..3
  const int kci  = lane & 15;

  const unsigned short* vg0 = Vtg + ((size_t)b * 64 + l15) * NKK + kstart + quad * 8;

  float4 kpre[4];
  uint4 vtpre[4];
#pragma unroll
  for (int c = 0; c < 4; ++c)
    kpre[c] = K4[(size_t)(b * NKK + kstart + c * 4 + krow) * 16 + kci];
#pragma unroll
  for (int nb = 0; nb < 4; ++nb)
    vtpre[nb] = *(const uint4*)(vg0 + (size_t)nb * 16 * NKK);

  const floatx4* qb = (const floatx4*)&qsA[lq * FSTRIDE];
  const floatx4* kb = (const floatx4*)&ksA[w][lk * FSTRIDE];

  bool pairUpd = false;

  // one 16-key subtile: stage K, prefetch next, score, online-softmax.
  auto subtile = [&](int st, int t) {
    // stage prefetched K subtile (16 rows) -> LDS (wave-private)
#pragma unroll
    for (int c = 0; c < 4; ++c)
      *(float4*)&ksA[w][(c * 4 + krow) * FSTRIDE + kci * 4] = kpre[c];
    // prefetch next subtile
    {
      const int stn = (st + 1 < 2 * PAIRS) ? st + 1 : st;
#pragma unroll
      for (int c = 0; c < 4; ++c)
        kpre[c] = K4[(size_t)(b * NKK + kstart + stn * 16 + c * 4 + krow) * 16 + kci];
    }
    // score: s[i][j] = sum_d |K[lk+8j] - Q[lq+8i]|
    float s[4][2];
#pragma unroll
    for (int i = 0; i < 4; ++i) { s[i][0] = 0.0f; s[i][1] = 0.0f; }
#pragma unroll
    for (int dc = 0; dc < 16; ++dc) {
      floatx4 qv[4], kv[2];
#pragma unroll
      for (int i = 0; i < 4; ++i) qv[i] = qb[i * (8 * FSTRIDE4) + dc];
#pragma unroll
      for (int j = 0; j < 2; ++j) kv[j] = kb[j * (8 * FSTRIDE4) + dc];
#pragma unroll
      for (int i = 0; i < 4; ++i) {
        const floatx2 qlo = qv[i].lo, qhi = qv[i].hi;
#pragma unroll
        for (int j = 0; j < 2; ++j) {
          floatx2 d0 = pk_sub(qlo, kv[j].lo);
          floatx2 d1 = pk_sub(qhi, kv[j].hi);
          s[i][j] += __builtin_fabsf(d0.x);
          s[i][j] += __builtin_fabsf(d0.y);
          s[i][j] += __builtin_fabsf(d1.x);
          s[i][j] += __builtin_fabsf(d1.y);
        }
      }
    }
    // online softmax (base-2); row max via min(s); skip alpha when no update
    float tm[4];
    bool upd = false;
#pragma unroll
    for (int i = 0; i < 4; ++i) {
      float sm = fminf(s[i][0], s[i][1]);
      sm = fminf(sm, __shfl_xor(sm, 1));
      sm = fminf(sm, __shfl_xor(sm, 2));
      sm = fminf(sm, __shfl_xor(sm, 4));
      tm[i] = sm * sm * NEG_HALF_LOG2E;
      upd = upd || (tm[i] > m_i[i]);
    }
    if (__any(upd ? 1 : 0)) {
      pairUpd = true;
      float al[4];
#pragma unroll
      for (int i = 0; i < 4; ++i) {
        const float mn = fmaxf(m_i[i], tm[i]);
        al[i] = fexp2(m_i[i] - mn);
        m_i[i] = mn;
        l_i[i] *= al[i];
      }
      if (t == 1) {
        // rescale this wave's stored subtile-0 P entries to the new m
#pragma unroll
        for (int i = 0; i < 4; ++i)
#pragma unroll
          for (int j = 0; j < 2; ++j) {
            const int idx = (lq + 8 * i) * PSTRIDE + lk + 8 * j;
            psB[w][idx] = f2bf(bf2f(psB[w][idx]) * al[i]);
          }
      }
    }
#pragma unroll
    for (int i = 0; i < 4; ++i) {
      float ps = 0.0f;
#pragma unroll
      for (int j = 0; j < 2; ++j) {
        const float sv = s[i][j];
        const float e = fexp2(fmaf(sv * NEG_HALF_LOG2E, sv, -m_i[i]));
        ps += e;
        psB[w][(lq + 8 * i) * PSTRIDE + 16 * t + lk + 8 * j] = f2bf(e);
      }
      l_i[i] += ps;
    }
  };

  for (int p = 0; p < PAIRS; ++p) {
    subtile(p * 2, 0);
    subtile(p * 2 + 1, 1);

    // ---- one P.V MFMA per 32-key pair ----
    if (pairUpd) {
      if (lk == 0) {
#pragma unroll
        for (int i = 0; i < 4; ++i)
          abA[w][lq + 8 * i] = fexp2(m_mfma[i] - m_i[i]);
      }
#pragma unroll
      for (int i = 0; i < 4; ++i) m_mfma[i] = m_i[i];
    }
    {
      bf16x8 afrag[2];
#pragma unroll
      for (int mb = 0; mb < 2; ++mb)
        afrag[mb] = *(const bf16x8*)&psB[w][(mb * 16 + l15) * PSTRIDE + quad * 8];
      if (pairUpd) {
        const floatx4 arv0 = *(const floatx4*)&abA[w][quad * 4];
        const floatx4 arv1 = *(const floatx4*)&abA[w][16 + quad * 4];
#pragma unroll
        for (int nb = 0; nb < 4; ++nb) { acc[0][nb] *= arv0; acc[1][nb] *= arv1; }
      }
#pragma unroll
      for (int nb = 0; nb < 4; ++nb) {
        bf16x8 bfrag = __builtin_bit_cast(bf16x8, vtpre[nb]);
        acc[0][nb] = __builtin_amdgcn_mfma_f32_16x16x32_bf16(afrag[0], bfrag, acc[0][nb], 0, 0, 0);
        acc[1][nb] = __builtin_amdgcn_mfma_f32_16x16x32_bf16(afrag[1], bfrag, acc[1][nb], 0, 0, 0);
      }
    }
    pairUpd = false;
    // prefetch next pair's V
    {
      const int pn = (p + 1 < PAIRS) ? p + 1 : p;
#pragma unroll
      for (int nb = 0; nb < 4; ++nb)
        vtpre[nb] = *(const uint4*)(vg0 + (size_t)nb * 16 * NKK + pn * 32);
    }
  }

  // ---- epilogue: l-reduce across lk; publish m,l (overlay psB); 2-phase O merge ----
#pragma unroll
  for (int i = 0; i < 4; ++i) {
    float l = l_i[i];
    l += __shfl_xor(l, 1);
    l += __shfl_xor(l, 2);
    l += __shfl_xor(l, 4);
    l_i[i] = l;
  }
  {
    float* mlb = (float*)&psB[w][0];   // psB[w] dead after final MFMA
    if (lk == 0) {
#pragma unroll
      for (int i = 0; i < 4; ++i) {
        mlb[lq + 8 * i]      = m_i[i];
        mlb[32 + lq + 8 * i] = l_i[i];
      }
    }
  }
  __syncthreads();

  // per-lane scale for own acc rows
  float swf[2][4];
#pragma unroll
  for (int mb = 0; mb < 2; ++mb)
#pragma unroll
    for (int r = 0; r < 4; ++r) {
      const int row = mb * 16 + quad * 4 + r;
      float mm[4];
#pragma unroll
      for (int ww = 0; ww < 4; ++ww) mm[ww] = ((const float*)&psB[ww][0])[row];
      const float M = fmaxf(fmaxf(mm[0], mm[1]), fmaxf(mm[2], mm[3]));
      swf[mb][r] = fexp2(mm[w] - M);
    }
  float* Ob = qsA;   // 32 x 68 merge buffer (qsA dead after last score)
#pragma unroll
  for (int t = 0; t < 4; ++t) {
    if (w == t) {
#pragma unroll
      for (int mb = 0; mb < 2; ++mb)
#pragma unroll
        for (int nb = 0; nb < 4; ++nb)
#pragma unroll
          for (int r = 0; r < 4; ++r) {
            const int row = mb * 16 + quad * 4 + r;
            const int col = nb * 16 + l15;
            const float v = acc[mb][nb][r] * swf[mb][r];
            if (t == 0) Ob[row * FSTRIDE + col] = v;
            else        Ob[row * FSTRIDE + col] += v;
          }
    }
    __syncthreads();
  }

  {
    const int q = tid >> 3;
    const int dbase = (tid & 7) * 8;
    float mm[4], ll[4];
#pragma unroll
    for (int ww = 0; ww < 4; ++ww) {
      mm[ww] = ((const float*)&psB[ww][0])[q];
      ll[ww] = ((const float*)&psB[ww][0])[32 + q];
    }
    const float M = fmaxf(fmaxf(mm[0], mm[1]), fmaxf(mm[2], mm[3]));
    float L = 0.0f;
#pragma unroll
    for (int ww = 0; ww < 4; ++ww) L += fexp2(mm[ww] - M) * ll[ww];
    if (PARTIAL) {
      const size_t pp = ((size_t)blockIdx.z * 4 + b) * 128 + blockIdx.x;
      if (dbase == 0) { Pm[pp * 32 + q] = M; Pl[pp * 32 + q] = L; }
      unsigned short* dst = POu + pp * 2048 + q * 64 + dbase;
      unsigned u[4];
#pragma unroll
      for (int c = 0; c < 4; ++c)
        u[c] = packbf(Ob[q * FSTRIDE + dbase + 2 * c], Ob[q * FSTRIDE + dbase + 2 * c + 1]);
      *(uint4*)dst = make_uint4(u[0], u[1], u[2], u[3]);
    } else {
      const float rL = 1.0f / L;
      const size_t gbase = (size_t)(b * NQQ + qt + q) * 64 + dbase;
#pragma unroll
      for (int c = 0; c < 8; ++c)
        outp[gbase + c] = Ob[q * FSTRIDE + dbase + c] * rL * Wog[gbase + c];
    }
  }
}

// ---------------------------------------------------------------------------
// Merge the 4 key-split partials (bf16 O): out = sum_s(w_s O_s)/L * Wo.
// ---------------------------------------------------------------------------
__global__ __launch_bounds__(256) void amerge_kernel(
    const float* __restrict__ Pm, const float* __restrict__ Pl,
    const unsigned short* __restrict__ POu, const float* __restrict__ Wog,
    float* __restrict__ outp)
{
  const int tid = threadIdx.x;
  const int qt = blockIdx.x;
  const int b = blockIdx.y;
  const int q = tid >> 3;
  const int dbase = (tid & 7) * 8;
  size_t p[4];
  float mv[4], lv[4];
#pragma unroll
  for (int s = 0; s < 4; ++s) {
    p[s] = ((size_t)s * 4 + b) * 128 + qt;
    mv[s] = Pm[p[s] * 32 + q];
    lv[s] = Pl[p[s] * 32 + q];
  }
  const float M = fmaxf(fmaxf(mv[0], mv[1]), fmaxf(mv[2], mv[3]));
  float wsum = 0.0f, wgt[4];
#pragma unroll
  for (int s = 0; s < 4; ++s) { wgt[s] = fexp2(mv[s] - M); wsum += wgt[s] * lv[s]; }
  const float rL = 1.0f / wsum;
  const size_t g = ((size_t)b * NQQ + qt * 32 + q) * 64 + dbase;
#pragma unroll
  for (int c = 0; c < 8; ++c) {
    float o = 0.0f;
#pragma unroll
    for (int s = 0; s < 4; ++s)
      o += wgt[s] * bf2f(POu[p[s] * 2048 + q * 64 + dbase + c]);
    outp[g + c] = o * rL * Wog[g + c];
  }
}

// ---------------------------------------------------------------------------
extern "C" void kernel_launch(void* const* d_in, const int* in_sizes, int n_in,
                              void* d_out, int out_size, void* d_ws, size_t ws_size,
                              hipStream_t stream) {
  (void)in_sizes; (void)n_in; (void)out_size;
  const float* KEY   = (const float*)d_in[0];
  const float* VALUE = (const float*)d_in[1];
  const float* QUERY = (const float*)d_in[2];
  const float* W1w = (const float*)d_in[3];
  const float* W1b = (const float*)d_in[4];
  const float* W2w = (const float*)d_in[5];
  const float* W2b = (const float*)d_in[6];
  const float* W3w = (const float*)d_in[7];
  const float* W3b = (const float*)d_in[8];
  const float* Wo1w = (const float*)d_in[9];
  const float* Wo1b = (const float*)d_in[10];
  const float* Wo2w = (const float*)d_in[11];
  const float* Wo2b = (const float*)d_in[12];
  const float* Wo3w = (const float*)d_in[13];
  const float* Wo3b = (const float*)d_in[14];

  float* ws = (float*)d_ws;
  const size_t tsz = (size_t)B_DIM * NKK * DD;  // 1,048,576 floats
  float* Ks = ws;
  float* Qs = ws + tsz;
  float* Wo = ws + 2 * tsz;
  unsigned short* Vtg = (unsigned short*)(ws + 3 * tsz);  // tsz ushorts (2 MB)
  unsigned short* sp  = Vtg + tsz;                        // 2x196608 ushorts
  float* Pm = ws + 3 * tsz + tsz / 2 + 196608;            // 16x128x32 partial maxes
  float* Pl = Pm + 65536;
  unsigned short* POu = (unsigned short*)(Pl + 65536);    // 16x128x2048 bf16
  float* outf = (float*)d_out;

  const size_t ws_need = (size_t)(3 * tsz + tsz / 2 + 196608 + 2 * 65536 + 2097152) * 4;
  const bool partial = ws_size >= ws_need;   // deterministic across calls

  wsplit_kernel<<<dim3(768), 256, 0, stream>>>(W1w, W2w, W3w, Wo1w, Wo2w, Wo3w, sp);
  vtrans_kernel<<<dim3(NKK / 64, B_DIM), 256, 0, stream>>>(VALUE, Vtg);
  mlpmm_kernel<<<dim3(768), 512, 0, stream>>>(
      KEY, QUERY, W1b, W2b, W3b, Wo1b, Wo2b, Wo3b, sp, Ks, Qs, Wo);
  if (partial) {
    attn_kernel<8, true><<<dim3(NQQ / 32, B_DIM, 4), 256, 0, stream>>>(
        Ks, Qs, Vtg, Wo, outf, Pm, Pl, POu);
    amerge_kernel<<<dim3(NQQ / 32, B_DIM), 256, 0, stream>>>(Pm, Pl, POu, Wo, outf);
  } else {
    attn_kernel<32, false><<<dim3(NQQ / 32, B_DIM, 1), 256, 0, stream>>>(
        Ks, Qs, Vtg, Wo, outf, Pm, Pl, POu);
  }
}